// Round 6
// baseline (87.474 us; speedup 1.0000x reference)
//
#include <hip/hip_runtime.h>
#include <math.h>

// out[t,b] = F(x[t,b]) — scalar function (zero-state LSTM cell x2 + linear).
// Build F-table (32768 entries over [-10,10]) each launch, then lerp.
//
// R6: (1) repack emits contiguous 336B per-row records [Wi|Wg|Wo|biases|wlin]
// so each wave's 3-4 rows are a handful of s_load_dwordx16 chains, not 12
// scattered streams; (2) NTAB 16k->32k => 512 blocks, launch_bounds(1024,8):
// 2 blocks/CU, 8 waves/SIMD — block B issues while block A drains barriers /
// s_load waits (R5 had 1 block/CU: nothing to overlap the two syncthreads).

#define NTAB 32768
#define XMIN (-10.0f)
#define XMAX (10.0f)

#define W2_STRIDE 84                 // dwords per layer-2 row record (336 B)
#define L1_OFF    (51 * W2_STRIDE)   // layer-1 records start (dwords)
#define L1_STRIDE 8
#define PACK_DWORDS (L1_OFF + 51 * L1_STRIDE)

typedef _Float16 h2_t __attribute__((ext_vector_type(2)));

__device__ __forceinline__ float bcf(unsigned u) { return __builtin_bit_cast(float, u); }
__device__ __forceinline__ h2_t  bch(unsigned u) { return __builtin_bit_cast(h2_t, u); }

__device__ __forceinline__ float fexp2_(float x) { return __builtin_amdgcn_exp2f(x); }
__device__ __forceinline__ float frcp_(float x)  { return __builtin_amdgcn_rcpf(x); }
// sigmoid(z) = 1/(1+2^(-z*log2 e)) ; tanh(z) = 1 - 2/(1+2^(2z*log2 e))
__device__ __forceinline__ float fsig_(float z)  { return frcp_(1.0f + fexp2_(-1.44269504f * z)); }
__device__ __forceinline__ float ftanh_(float z) { return 1.0f - 2.0f * frcp_(1.0f + fexp2_(2.88539008f * z)); }

// Gate rows (torch LSTMCell order i,f,g,o; f dead since c_prev=0).
// Row-j record: dwords [0,26)=Wi f16x2, [26,52)=Wg, [52,78)=Wo,
// 78..80 = bias sums (i,g,o) as f32, 81 = w_lin[j], 82-83 pad.
// Layer-1 record (at L1_OFF + j*8): [w1i,w1g,w1o, b1i,b1g,b1o, pad, pad].
__global__ __launch_bounds__(128) void repack(
    const float* __restrict__ w_ih1, const float* __restrict__ b_ih1, const float* __restrict__ b_hh1,
    const float* __restrict__ w_ih2, const float* __restrict__ b_ih2, const float* __restrict__ b_hh2,
    const float* __restrict__ w_lin, unsigned* __restrict__ P)
{
    const int j = blockIdx.x;        // 0..50
    const int t = threadIdx.x;
    unsigned* R = P + j * W2_STRIDE;
    if (t < 78) {
        int g = t / 26, p = t - g * 26;
        int src = j + (g == 0 ? 0 : (g == 1 ? 102 : 153));
        float a = w_ih2[src * 51 + 2 * p];
        float b = (2 * p + 1 < 51) ? w_ih2[src * 51 + 2 * p + 1] : 0.0f;
        h2_t h;
        h.x = (_Float16)a;   // RTE cvt (unbiased)
        h.y = (_Float16)b;
        R[t] = __builtin_bit_cast(unsigned, h);
    } else if (t < 81) {
        int g = t - 78;
        int src = j + (g == 0 ? 0 : (g == 1 ? 102 : 153));
        R[t] = __builtin_bit_cast(unsigned, b_ih2[src] + b_hh2[src]);
    } else if (t == 81) {
        R[81] = __builtin_bit_cast(unsigned, w_lin[j]);
    } else if (t >= 88 && t < 94) {
        int q  = t - 88;                       // 0..5
        int gq = (q < 3) ? q : q - 3;
        int src = j + (gq == 0 ? 0 : (gq == 1 ? 102 : 153));
        float v = (q < 3) ? w_ih1[src] : (b_ih1[src] + b_hh1[src]);
        (P + L1_OFF + j * L1_STRIDE)[q] = __builtin_bit_cast(unsigned, v);
    }
}

__global__ __launch_bounds__(1024, 8) void build_table(
    const unsigned* __restrict__ P, const float* __restrict__ b_lin,
    float* __restrict__ table)
{
    __shared__ float h1s[51][64];     // h1 shared across waves: [j][lane] conflict-free
    __shared__ float sPart[16][64];

    const int tid  = threadIdx.x;
    const int lane = tid & 63;
    // readfirstlane: wave id provably uniform -> record addresses scalarize to s_load.
    const int wave = __builtin_amdgcn_readfirstlane(tid >> 6);

    const int   e = blockIdx.x * 64 + lane;          // 512 blocks x 64 entries = NTAB
    const float x = XMIN + (XMAX - XMIN) * ((float)e / (float)(NTAB - 1));

    // Contiguous row chunk for this wave: 3 or 4 rows.
    const int j0 = (51 * wave) >> 4;
    const int j1 = (51 * (wave + 1)) >> 4;

    // ---- Phase 1: layer-1 once per block, contiguous row chunks ----
    for (int j = j0; j < j1; ++j) {
        const unsigned* __restrict__ L = P + L1_OFF + j * L1_STRIDE;
        float gi = fmaf(x, bcf(L[0]), bcf(L[3]));
        float gg = fmaf(x, bcf(L[1]), bcf(L[4]));
        float go = fmaf(x, bcf(L[2]), bcf(L[5]));
        float c  = fsig_(gi) * ftanh_(gg);
        h1s[j][lane] = fsig_(go) * ftanh_(c);
    }
    __syncthreads();

    // ---- Pack this lane's h1 vector to f16 pairs (26 VGPRs) ----
    h2_t h1p[26];
    #pragma unroll
    for (int p = 0; p < 26; ++p) {
        float a = h1s[2 * p][lane];
        float b = (2 * p + 1 < 51) ? h1s[2 * p + 1][lane] : 0.0f;
        h2_t h;
        h.x = (_Float16)a;
        h.y = (_Float16)b;
        h1p[p] = h;
    }

    // ---- Phase 2: contiguous per-row records via v_dot2_f32_f16 ----
    float part = 0.0f;
    for (int j = j0; j < j1; ++j) {
        const unsigned* __restrict__ R = P + j * W2_STRIDE;
        float gi = bcf(R[78]);
        float gg = bcf(R[79]);
        float go = bcf(R[80]);
        #pragma unroll
        for (int p = 0; p < 26; ++p) {
            gi = __builtin_amdgcn_fdot2(h1p[p], bch(R[p]),      gi, false);
            gg = __builtin_amdgcn_fdot2(h1p[p], bch(R[26 + p]), gg, false);
            go = __builtin_amdgcn_fdot2(h1p[p], bch(R[52 + p]), go, false);
        }
        float c2  = fsig_(gi) * ftanh_(gg);
        float h2v = fsig_(go) * ftanh_(c2);
        part = fmaf(h2v, bcf(R[81]), part);
    }

    sPart[wave][lane] = part;
    __syncthreads();
    if (wave == 0) {
        float out = b_lin[0];
        #pragma unroll
        for (int w = 0; w < 16; ++w) out += sPart[w][lane];
        table[e] = out;
    }
}

__device__ __forceinline__ float lerp_tab(float x, const float* __restrict__ t) {
    const float inv_h = (float)(NTAB - 1) / (XMAX - XMIN);
    float u = (x - XMIN) * inv_h;
    u = fminf(fmaxf(u, 0.0f), (float)(NTAB - 1) - 0.001f);
    int   i0 = (int)u;
    float f  = u - (float)i0;
    float t0 = t[i0];
    float t1 = t[i0 + 1];
    return fmaf(f, t1 - t0, t0);
}

__global__ __launch_bounds__(256) void lookup_kernel(
    const float* __restrict__ x, const float* __restrict__ table,
    float* __restrict__ out, int n)
{
    int i4 = blockIdx.x * 256 + threadIdx.x;
    int base = i4 * 4;
    if (base + 3 < n) {
        float4 xv = ((const float4*)x)[i4];
        float4 r;
        r.x = lerp_tab(xv.x, table);
        r.y = lerp_tab(xv.y, table);
        r.z = lerp_tab(xv.z, table);
        r.w = lerp_tab(xv.w, table);
        ((float4*)out)[i4] = r;
    } else {
        for (int i = base; i < n; ++i) out[i] = lerp_tab(x[i], table);
    }
}

extern "C" void kernel_launch(void* const* d_in, const int* in_sizes, int n_in,
                              void* d_out, int out_size, void* d_ws, size_t ws_size,
                              hipStream_t stream) {
    const float* x     = (const float*)d_in[0];
    const float* w_ih1 = (const float*)d_in[1];
    // d_in[2] = w_hh1 (unused: h_prev = 0)
    const float* b_ih1 = (const float*)d_in[3];
    const float* b_hh1 = (const float*)d_in[4];
    const float* w_ih2 = (const float*)d_in[5];
    // d_in[6] = w_hh2 (unused)
    const float* b_ih2 = (const float*)d_in[7];
    const float* b_hh2 = (const float*)d_in[8];
    const float* w_lin = (const float*)d_in[9];
    const float* b_lin = (const float*)d_in[10];

    float* out = (float*)d_out;
    // d_ws layout (dwords): [0, NTAB) table | [NTAB, NTAB+PACK_DWORDS) records
    float*    table = (float*)d_ws;
    unsigned* P     = (unsigned*)d_ws + NTAB;
    const int n = in_sizes[0];     // T*B = 409600

    repack<<<51, 128, 0, stream>>>(w_ih1, b_ih1, b_hh1, w_ih2, b_ih2, b_hh2, w_lin, P);

    build_table<<<NTAB / 64, 1024, 0, stream>>>(P, b_lin, table);

    const int n4 = (n + 3) / 4;
    lookup_kernel<<<(n4 + 255) / 256, 256, 0, stream>>>(x, table, out, n);
}

// Round 7
// 87.153 us; speedup vs baseline: 1.0037x; 1.0037x over previous
//
#include <hip/hip_runtime.h>
#include <math.h>

// out[t,b] = F(x[t,b]) — scalar function (zero-state LSTM cell x2 + linear).
// Build F-table (16384 entries over [-10,10]) each launch, then lerp.
//
// R7: revert R6's NTAB doubling (it doubled total build work: +3.3us), keep
// R6's contiguous 336B per-row records (s_load_dwordx16 batching), and add
// pre-barrier prefetch: each wave reads its first phase-2 row's biases/wlin
// before __syncthreads so the s_load latency hides under phase-1 compute +
// barrier drain. Ledger: controllable slice ~11-13us; fill of 268MB d_ws
// (40us @85% HBM) + harness restores (~30us) are fixed.

#define NTAB 16384
#define XMIN (-10.0f)
#define XMAX (10.0f)

#define W2_STRIDE 84                 // dwords per layer-2 row record (336 B)
#define L1_OFF    (51 * W2_STRIDE)   // layer-1 records start (dwords)
#define L1_STRIDE 8
#define PACK_DWORDS (L1_OFF + 51 * L1_STRIDE)

typedef _Float16 h2_t __attribute__((ext_vector_type(2)));

__device__ __forceinline__ float bcf(unsigned u) { return __builtin_bit_cast(float, u); }
__device__ __forceinline__ h2_t  bch(unsigned u) { return __builtin_bit_cast(h2_t, u); }

__device__ __forceinline__ float fexp2_(float x) { return __builtin_amdgcn_exp2f(x); }
__device__ __forceinline__ float frcp_(float x)  { return __builtin_amdgcn_rcpf(x); }
// sigmoid(z) = 1/(1+2^(-z*log2 e)) ; tanh(z) = 1 - 2/(1+2^(2z*log2 e))
__device__ __forceinline__ float fsig_(float z)  { return frcp_(1.0f + fexp2_(-1.44269504f * z)); }
__device__ __forceinline__ float ftanh_(float z) { return 1.0f - 2.0f * frcp_(1.0f + fexp2_(2.88539008f * z)); }

// Gate rows (torch LSTMCell order i,f,g,o; f dead since c_prev=0).
// Row-j record: dwords [0,26)=Wi f16x2, [26,52)=Wg, [52,78)=Wo,
// 78..80 = bias sums (i,g,o) as f32, 81 = w_lin[j], 82-83 pad.
// Layer-1 record (at L1_OFF + j*8): [w1i,w1g,w1o, b1i,b1g,b1o, pad, pad].
__global__ __launch_bounds__(128) void repack(
    const float* __restrict__ w_ih1, const float* __restrict__ b_ih1, const float* __restrict__ b_hh1,
    const float* __restrict__ w_ih2, const float* __restrict__ b_ih2, const float* __restrict__ b_hh2,
    const float* __restrict__ w_lin, unsigned* __restrict__ P)
{
    const int j = blockIdx.x;        // 0..50
    const int t = threadIdx.x;
    unsigned* R = P + j * W2_STRIDE;
    if (t < 78) {
        int g = t / 26, p = t - g * 26;
        int src = j + (g == 0 ? 0 : (g == 1 ? 102 : 153));
        float a = w_ih2[src * 51 + 2 * p];
        float b = (2 * p + 1 < 51) ? w_ih2[src * 51 + 2 * p + 1] : 0.0f;
        h2_t h;
        h.x = (_Float16)a;   // RTE cvt (unbiased)
        h.y = (_Float16)b;
        R[t] = __builtin_bit_cast(unsigned, h);
    } else if (t < 81) {
        int g = t - 78;
        int src = j + (g == 0 ? 0 : (g == 1 ? 102 : 153));
        R[t] = __builtin_bit_cast(unsigned, b_ih2[src] + b_hh2[src]);
    } else if (t == 81) {
        R[81] = __builtin_bit_cast(unsigned, w_lin[j]);
    } else if (t >= 88 && t < 94) {
        int q  = t - 88;                       // 0..5
        int gq = (q < 3) ? q : q - 3;
        int src = j + (gq == 0 ? 0 : (gq == 1 ? 102 : 153));
        float v = (q < 3) ? w_ih1[src] : (b_ih1[src] + b_hh1[src]);
        (P + L1_OFF + j * L1_STRIDE)[q] = __builtin_bit_cast(unsigned, v);
    }
}

__global__ __launch_bounds__(1024, 4) void build_table(
    const unsigned* __restrict__ P, const float* __restrict__ b_lin,
    float* __restrict__ table)
{
    __shared__ float h1s[51][64];     // h1 shared across waves: [j][lane] conflict-free
    __shared__ float sPart[16][64];

    const int tid  = threadIdx.x;
    const int lane = tid & 63;
    // readfirstlane: wave id provably uniform -> record addresses scalarize to s_load.
    const int wave = __builtin_amdgcn_readfirstlane(tid >> 6);

    const int   e = blockIdx.x * 64 + lane;          // 256 blocks x 64 entries = NTAB
    const float x = XMIN + (XMAX - XMIN) * ((float)e / (float)(NTAB - 1));

    // Contiguous row chunk for this wave: 3 or 4 rows.
    const int j0 = (51 * wave) >> 4;
    const int j1 = (51 * (wave + 1)) >> 4;

    // Pre-barrier prefetch: first phase-2 row's scalars are LDS-independent,
    // issue their s_loads now so the latency hides under phase 1 + barrier.
    const unsigned* __restrict__ R0 = P + j0 * W2_STRIDE;
    float pf_gi = bcf(R0[78]);
    float pf_gg = bcf(R0[79]);
    float pf_go = bcf(R0[80]);
    float pf_wl = bcf(R0[81]);

    // ---- Phase 1: layer-1 once per block, contiguous row chunks ----
    for (int j = j0; j < j1; ++j) {
        const unsigned* __restrict__ L = P + L1_OFF + j * L1_STRIDE;
        float gi = fmaf(x, bcf(L[0]), bcf(L[3]));
        float gg = fmaf(x, bcf(L[1]), bcf(L[4]));
        float go = fmaf(x, bcf(L[2]), bcf(L[5]));
        float c  = fsig_(gi) * ftanh_(gg);
        h1s[j][lane] = fsig_(go) * ftanh_(c);
    }
    __syncthreads();

    // ---- Pack this lane's h1 vector to f16 pairs (26 VGPRs) ----
    h2_t h1p[26];
    #pragma unroll
    for (int p = 0; p < 26; ++p) {
        float a = h1s[2 * p][lane];
        float b = (2 * p + 1 < 51) ? h1s[2 * p + 1][lane] : 0.0f;
        h2_t h;
        h.x = (_Float16)a;
        h.y = (_Float16)b;
        h1p[p] = h;
    }

    // ---- Phase 2: contiguous per-row records via v_dot2_f32_f16 ----
    float part = 0.0f;
    for (int j = j0; j < j1; ++j) {
        const unsigned* __restrict__ R = P + j * W2_STRIDE;
        float gi, gg, go, wl;
        if (j == j0) { gi = pf_gi; gg = pf_gg; go = pf_go; wl = pf_wl; }
        else         { gi = bcf(R[78]); gg = bcf(R[79]); go = bcf(R[80]); wl = bcf(R[81]); }
        #pragma unroll
        for (int p = 0; p < 26; ++p) {
            gi = __builtin_amdgcn_fdot2(h1p[p], bch(R[p]),      gi, false);
            gg = __builtin_amdgcn_fdot2(h1p[p], bch(R[26 + p]), gg, false);
            go = __builtin_amdgcn_fdot2(h1p[p], bch(R[52 + p]), go, false);
        }
        float c2  = fsig_(gi) * ftanh_(gg);
        float h2v = fsig_(go) * ftanh_(c2);
        part = fmaf(h2v, wl, part);
    }

    sPart[wave][lane] = part;
    __syncthreads();
    if (wave == 0) {
        float out = b_lin[0];
        #pragma unroll
        for (int w = 0; w < 16; ++w) out += sPart[w][lane];
        table[e] = out;
    }
}

__device__ __forceinline__ float lerp_tab(float x, const float* __restrict__ t) {
    const float inv_h = (float)(NTAB - 1) / (XMAX - XMIN);
    float u = (x - XMIN) * inv_h;
    u = fminf(fmaxf(u, 0.0f), (float)(NTAB - 1) - 0.001f);
    int   i0 = (int)u;
    float f  = u - (float)i0;
    float t0 = t[i0];
    float t1 = t[i0 + 1];
    return fmaf(f, t1 - t0, t0);
}

__global__ __launch_bounds__(256) void lookup_kernel(
    const float* __restrict__ x, const float* __restrict__ table,
    float* __restrict__ out, int n)
{
    int i4 = blockIdx.x * 256 + threadIdx.x;
    int base = i4 * 4;
    if (base + 3 < n) {
        float4 xv = ((const float4*)x)[i4];
        float4 r;
        r.x = lerp_tab(xv.x, table);
        r.y = lerp_tab(xv.y, table);
        r.z = lerp_tab(xv.z, table);
        r.w = lerp_tab(xv.w, table);
        ((float4*)out)[i4] = r;
    } else {
        for (int i = base; i < n; ++i) out[i] = lerp_tab(x[i], table);
    }
}

extern "C" void kernel_launch(void* const* d_in, const int* in_sizes, int n_in,
                              void* d_out, int out_size, void* d_ws, size_t ws_size,
                              hipStream_t stream) {
    const float* x     = (const float*)d_in[0];
    const float* w_ih1 = (const float*)d_in[1];
    // d_in[2] = w_hh1 (unused: h_prev = 0)
    const float* b_ih1 = (const float*)d_in[3];
    const float* b_hh1 = (const float*)d_in[4];
    const float* w_ih2 = (const float*)d_in[5];
    // d_in[6] = w_hh2 (unused)
    const float* b_ih2 = (const float*)d_in[7];
    const float* b_hh2 = (const float*)d_in[8];
    const float* w_lin = (const float*)d_in[9];
    const float* b_lin = (const float*)d_in[10];

    float* out = (float*)d_out;
    // d_ws layout (dwords): [0, NTAB) table | [NTAB, NTAB+PACK_DWORDS) records
    float*    table = (float*)d_ws;
    unsigned* P     = (unsigned*)d_ws + NTAB;
    const int n = in_sizes[0];     // T*B = 409600

    repack<<<51, 128, 0, stream>>>(w_ih1, b_ih1, b_hh1, w_ih2, b_ih2, b_hh2, w_lin, P);

    build_table<<<NTAB / 64, 1024, 0, stream>>>(P, b_lin, table);

    const int n4 = (n + 3) / 4;
    lookup_kernel<<<(n4 + 255) / 256, 256, 0, stream>>>(x, table, out, n);
}

// Round 8
// 84.921 us; speedup vs baseline: 1.0301x; 1.0263x over previous
//
#include <hip/hip_runtime.h>
#include <math.h>

// out[t,b] = F(x[t,b]) — scalar function (zero-state LSTM cell x2 + linear).
// Build F-table (16384 entries over [-10,10]) each launch, then lerp.
//
// R8: exact revert to R5 (best measured: 84.2us). R6/R7's contiguous-record
// layout never beat it (87.2-87.5), and R7 showed the NTAB doubling wasn't
// the cause — either the single serial record chain pipelines worse than
// R5's 12 independent s_load streams, or variants are within +-3us noise.
// This A/B discriminates. Ledger: ~70us fixed harness reset (268MB d_ws
// poison @85% HBM + ~30us restores); controllable ~13-16us.

#define NTAB 16384
#define XMIN (-10.0f)
#define XMAX (10.0f)

typedef _Float16 h2_t __attribute__((ext_vector_type(2)));

__device__ __forceinline__ float fexp2_(float x) { return __builtin_amdgcn_exp2f(x); }
__device__ __forceinline__ float frcp_(float x)  { return __builtin_amdgcn_rcpf(x); }
// sigmoid(z) = 1/(1+2^(-z*log2 e)) ; tanh(z) = 1 - 2/(1+2^(2z*log2 e))
__device__ __forceinline__ float fsig_(float z)  { return frcp_(1.0f + fexp2_(-1.44269504f * z)); }
__device__ __forceinline__ float ftanh_(float z) { return 1.0f - 2.0f * frcp_(1.0f + fexp2_(2.88539008f * z)); }

// Live rows of w_ih2 (torch gate order i,f,g,o; f dead since c_prev=0):
// packed row r: r in [0,51) = i-gate j=r ; [51,102) = g-gate ; [102,153) = o-gate.
__global__ __launch_bounds__(256) void repack(
    const float* __restrict__ w_ih2, const float* __restrict__ b_ih2,
    const float* __restrict__ b_hh2, unsigned int* __restrict__ Wp,
    float* __restrict__ B2)
{
    int g = blockIdx.x * 256 + threadIdx.x;
    if (g < 153 * 26) {
        int r = g / 26;
        int p = g - r * 26;
        int src = (r < 51) ? r : r + 51;
        float a = w_ih2[src * 51 + 2 * p];
        float b = (2 * p + 1 < 51) ? w_ih2[src * 51 + 2 * p + 1] : 0.0f;
        h2_t h;
        h.x = (_Float16)a;   // RTE via v_cvt_f16_f32 (not pkrtz/RTZ: unbiased)
        h.y = (_Float16)b;
        Wp[r * 26 + p] = __builtin_bit_cast(unsigned int, h);
    }
    if (g < 153) {
        int src = (g < 51) ? g : g + 51;
        B2[g] = b_ih2[src] + b_hh2[src];
    }
}

__global__ __launch_bounds__(1024, 4) void build_table(
    const float* __restrict__ w_ih1, const float* __restrict__ b_ih1, const float* __restrict__ b_hh1,
    const unsigned int* __restrict__ Wp, const float* __restrict__ B2,
    const float* __restrict__ w_lin, const float* __restrict__ b_lin,
    float* __restrict__ table)
{
    __shared__ float h1s[51][64];     // h1 shared across waves: [j][lane] conflict-free
    __shared__ float sPart[16][64];

    const int tid  = threadIdx.x;
    const int lane = tid & 63;
    // readfirstlane: wave id provably uniform -> weight addresses scalarize to s_load.
    const int wave = __builtin_amdgcn_readfirstlane(tid >> 6);

    const int   e = blockIdx.x * 64 + lane;          // 256 blocks x 64 entries = NTAB
    const float x = XMIN + (XMAX - XMIN) * ((float)e / (float)(NTAB - 1));

    // ---- Phase 1: layer-1 once per block, j-rows split over 16 waves ----
    for (int j = wave; j < 51; j += 16) {
        float gi = fmaf(x, w_ih1[j],       b_ih1[j]       + b_hh1[j]);
        float gg = fmaf(x, w_ih1[j + 102], b_ih1[j + 102] + b_hh1[j + 102]);
        float go = fmaf(x, w_ih1[j + 153], b_ih1[j + 153] + b_hh1[j + 153]);
        float c  = fsig_(gi) * ftanh_(gg);
        h1s[j][lane] = fsig_(go) * ftanh_(c);
    }
    __syncthreads();

    // ---- Pack this lane's h1 vector to f16 pairs (26 VGPRs) ----
    h2_t h1p[26];
    #pragma unroll
    for (int p = 0; p < 26; ++p) {
        float a = h1s[2 * p][lane];
        float b = (2 * p + 1 < 51) ? h1s[2 * p + 1][lane] : 0.0f;
        h2_t h;
        h.x = (_Float16)a;
        h.y = (_Float16)b;
        h1p[p] = h;
    }

    // ---- Phase 2: each wave does 3-4 rows via v_dot2_f32_f16 ----
    float part = 0.0f;
    for (int j = wave; j < 51; j += 16) {
        const unsigned int* __restrict__ Wi = Wp + j * 26;
        const unsigned int* __restrict__ Wg = Wp + (51 + j) * 26;
        const unsigned int* __restrict__ Wo = Wp + (102 + j) * 26;
        float gi = B2[j];
        float gg = B2[51 + j];
        float go = B2[102 + j];
        #pragma unroll
        for (int p = 0; p < 26; ++p) {
            gi = __builtin_amdgcn_fdot2(h1p[p], __builtin_bit_cast(h2_t, Wi[p]), gi, false);
            gg = __builtin_amdgcn_fdot2(h1p[p], __builtin_bit_cast(h2_t, Wg[p]), gg, false);
            go = __builtin_amdgcn_fdot2(h1p[p], __builtin_bit_cast(h2_t, Wo[p]), go, false);
        }
        float c2  = fsig_(gi) * ftanh_(gg);
        float h2v = fsig_(go) * ftanh_(c2);
        part = fmaf(h2v, w_lin[j], part);
    }

    sPart[wave][lane] = part;
    __syncthreads();
    if (wave == 0) {
        float out = b_lin[0];
        #pragma unroll
        for (int w = 0; w < 16; ++w) out += sPart[w][lane];
        table[e] = out;
    }
}

__device__ __forceinline__ float lerp_tab(float x, const float* __restrict__ t) {
    const float inv_h = (float)(NTAB - 1) / (XMAX - XMIN);
    float u = (x - XMIN) * inv_h;
    u = fminf(fmaxf(u, 0.0f), (float)(NTAB - 1) - 0.001f);
    int   i0 = (int)u;
    float f  = u - (float)i0;
    float t0 = t[i0];
    float t1 = t[i0 + 1];
    return fmaf(f, t1 - t0, t0);
}

__global__ __launch_bounds__(256) void lookup_kernel(
    const float* __restrict__ x, const float* __restrict__ table,
    float* __restrict__ out, int n)
{
    int i4 = blockIdx.x * 256 + threadIdx.x;
    int base = i4 * 4;
    if (base + 3 < n) {
        float4 xv = ((const float4*)x)[i4];
        float4 r;
        r.x = lerp_tab(xv.x, table);
        r.y = lerp_tab(xv.y, table);
        r.z = lerp_tab(xv.z, table);
        r.w = lerp_tab(xv.w, table);
        ((float4*)out)[i4] = r;
    } else {
        for (int i = base; i < n; ++i) out[i] = lerp_tab(x[i], table);
    }
}

extern "C" void kernel_launch(void* const* d_in, const int* in_sizes, int n_in,
                              void* d_out, int out_size, void* d_ws, size_t ws_size,
                              hipStream_t stream) {
    const float* x     = (const float*)d_in[0];
    const float* w_ih1 = (const float*)d_in[1];
    // d_in[2] = w_hh1 (unused: h_prev = 0)
    const float* b_ih1 = (const float*)d_in[3];
    const float* b_hh1 = (const float*)d_in[4];
    const float* w_ih2 = (const float*)d_in[5];
    // d_in[6] = w_hh2 (unused)
    const float* b_ih2 = (const float*)d_in[7];
    const float* b_hh2 = (const float*)d_in[8];
    const float* w_lin = (const float*)d_in[9];
    const float* b_lin = (const float*)d_in[10];

    float* out = (float*)d_out;
    // d_ws layout (dwords): [0,16384) table | [16384, 16384+3978) packed W2 | then 153 bias sums
    float*        table = (float*)d_ws;
    unsigned int* Wp    = (unsigned int*)d_ws + 16384;
    float*        B2    = (float*)d_ws + 16384 + 153 * 26;
    const int n = in_sizes[0];     // T*B = 409600

    repack<<<(153 * 26 + 255) / 256, 256, 0, stream>>>(w_ih2, b_ih2, b_hh2, Wp, B2);

    build_table<<<NTAB / 64, 1024, 0, stream>>>(
        w_ih1, b_ih1, b_hh1, Wp, B2, w_lin, b_lin, table);

    const int n4 = (n + 3) / 4;
    lookup_kernel<<<(n4 + 255) / 256, 256, 0, stream>>>(x, table, out, n);
}